// Round 6
// baseline (38.073 us; speedup 1.0000x reference)
//
#include <hip/hip_runtime.h>

// Problem constants (from reference): B=8, L=4096, D=1024, MAX_CHUNKS=128
#define B_DIM 8
#define L_DIM 4096
#define D_DIM 1024
#define MAXC 128
#define ROWS 32                      // rows per balanced tile
#define TPB (L_DIM / ROWS)           // tiles per batch = 128
#define SLOTS 33                     // max distinct segs per 32-row tile (+1)

__device__ __forceinline__ void f4add(float4& a, const float4& v) {
    a.x += v.x; a.y += v.y; a.z += v.z; a.w += v.w;
}

// ---------------------------------------------------------------------------
// Kernel A: per batch (8 blocks x 256 threads):
//   - boundary positions pos[B][*] + count nseg[B] (block scan + scatter)
//   - UNCLAMPED per-token segment id seg[B][L] (= cumsum(mask)-1, in [-1, n))
// ---------------------------------------------------------------------------
__global__ void boundaries_kernel(const float* __restrict__ bnd,
                                  int* __restrict__ seg,    // [B][L] unclamped
                                  int* __restrict__ pos,    // [B][L]
                                  int* __restrict__ nseg)   // [B]
{
    const int b = blockIdx.x;
    const int t = threadIdx.x;           // 0..255
    const float* p = bnd + (size_t)b * L_DIM;
    const int base = t * 16;

    unsigned m = 0u;
#pragma unroll
    for (int j = 0; j < 16; ++j) {
        m |= (p[base + j] > 0.5f) ? (1u << j) : 0u;
    }
    int cnt = __popc(m);

    __shared__ int s[256];
    s[t] = cnt;
    __syncthreads();
    for (int off = 1; off < 256; off <<= 1) {
        int v = (t >= off) ? s[t - off] : 0;
        __syncthreads();
        s[t] += v;
        __syncthreads();
    }
    const int excl = s[t] - cnt;

    // boundary positions (scatter)
    {
        int* op = pos + (size_t)b * L_DIM;
        int idx = excl;
#pragma unroll
        for (int j = 0; j < 16; ++j) {
            if (m & (1u << j)) op[idx++] = base + j;
        }
    }

    // unclamped per-token seg ids, packed int4 stores
    {
        int c = excl;
        int4* sp = reinterpret_cast<int4*>(seg + (size_t)b * L_DIM + base);
#pragma unroll
        for (int q = 0; q < 4; ++q) {
            int vals[4];
#pragma unroll
            for (int j = 0; j < 4; ++j) {
                if (m & (1u << (q * 4 + j))) ++c;
                vals[j] = c - 1;
            }
            int4 w; w.x = vals[0]; w.y = vals[1]; w.z = vals[2]; w.w = vals[3];
            sp[q] = w;
        }
    }

    if (t == 255) nseg[b] = s[255];
}

// ---------------------------------------------------------------------------
// Kernel B: balanced pooling, NO atomics. One block per 32-row tile (1024
// identical blocks x 256 threads; each thread one float4 column slice).
// Within a tile, seg ids are consecutive (cumsum), so each run of equal seg
// flushes its partial sum to a private slot partials[tile][seg - s0].
// Block-uniform control flow; one coalesced 4 KB store per run.
// ---------------------------------------------------------------------------
__global__ void pool_tiles_kernel(const float* __restrict__ x,
                                  const int* __restrict__ seg,
                                  float* __restrict__ partials) // [B*TPB][SLOTS][D]
{
    const int tile = blockIdx.x;               // b*TPB + tt
    const int b    = tile >> 7;
    const int r0   = (tile & (TPB - 1)) * ROWS;
    const int t    = threadIdx.x;              // 0..255

    __shared__ int sseg[ROWS];
    if (t < ROWS) sseg[t] = seg[(size_t)b * L_DIM + r0 + t];
    __syncthreads();

    const int s0 = sseg[0];
    const float* xp = x + ((size_t)b * L_DIM + r0) * D_DIM + t * 4;
    float* pbase = partials + (size_t)tile * SLOTS * D_DIM + t * 4;

    float4 acc = make_float4(0.f, 0.f, 0.f, 0.f);
    int cur = s0;

    for (int rr = 0; rr < ROWS; rr += 8) {
        float4 vbuf[8];
#pragma unroll
        for (int j = 0; j < 8; ++j) {
            vbuf[j] = *reinterpret_cast<const float4*>(xp + (size_t)(rr + j) * D_DIM);
        }
#pragma unroll
        for (int j = 0; j < 8; ++j) {
            const int s = sseg[rr + j];
            if (s != cur) {
                if (cur >= 0 && cur < MAXC) {
                    *reinterpret_cast<float4*>(pbase + (size_t)(cur - s0) * D_DIM) = acc;
                }
                acc = make_float4(0.f, 0.f, 0.f, 0.f);
                cur = s;
            }
            f4add(acc, vbuf[j]);
        }
    }
    if (cur >= 0 && cur < MAXC) {
        *reinterpret_cast<float4*>(pbase + (size_t)(cur - s0) * D_DIM) = acc;
    }
}

// ---------------------------------------------------------------------------
// Kernel C: combine. One block per (b, chunk): gather partials from the
// <= (len/32)+1 spanning tiles (slot = c - seg[tile_first_row]), divide by
// count, write means + count. Empty chunks write zeros (d_out is poisoned).
// ---------------------------------------------------------------------------
__global__ void combine_kernel(const float* __restrict__ partials,
                               const int* __restrict__ seg,
                               const int* __restrict__ pos,
                               const int* __restrict__ nseg,
                               float* __restrict__ out_means,  // [B][MAXC][D]
                               float* __restrict__ out_cnts)   // [B][MAXC]
{
    const int bc = blockIdx.x;          // 0 .. B*MAXC-1
    const int b  = bc >> 7;
    const int c  = bc & (MAXC - 1);
    const int t  = threadIdx.x;         // 0..255

    const int n = nseg[b];

    float4 acc = make_float4(0.f, 0.f, 0.f, 0.f);
    int cnt = 0;

    if (c < n) {
        const int* pp = pos + (size_t)b * L_DIM;
        const int start = pp[c];
        const int end   = (c + 1 < n) ? pp[c + 1] : L_DIM;
        cnt = end - start;

        const int t0 = start >> 5;
        const int t1 = (end - 1) >> 5;
        for (int tt = t0; tt <= t1; ++tt) {
            const int s0 = seg[(size_t)b * L_DIM + tt * ROWS];
            const float* pp4 = partials
                + ((size_t)(b * TPB + tt) * SLOTS + (size_t)(c - s0)) * D_DIM + t * 4;
            f4add(acc, *reinterpret_cast<const float4*>(pp4));
        }
        const float inv = 1.0f / (float)cnt;
        acc.x *= inv; acc.y *= inv; acc.z *= inv; acc.w *= inv;
    }

    float4* op = reinterpret_cast<float4*>(out_means + (size_t)bc * D_DIM) + t;
    *op = acc;
    if (t == 0) out_cnts[bc] = (float)cnt;
}

extern "C" void kernel_launch(void* const* d_in, const int* in_sizes, int n_in,
                              void* d_out, int out_size, void* d_ws, size_t ws_size,
                              hipStream_t stream)
{
    const float* x   = (const float*)d_in[0];   // [B, L, D] fp32
    const float* bnd = (const float*)d_in[1];   // [B, L]    fp32

    float* out = (float*)d_out;
    float* out_means = out;                                // B*MAXC*D floats
    float* out_cnts  = out + (size_t)B_DIM * MAXC * D_DIM; // B*MAXC floats

    // workspace: seg[B][L], pos[B][L], nseg[B] ints; then partials (~138 MB)
    int* seg  = (int*)d_ws;
    int* pos  = seg + (size_t)B_DIM * L_DIM;
    int* nseg = pos + (size_t)B_DIM * L_DIM;
    // 2*B*L + B = 65544 ints = 262176 bytes, 16B-aligned
    float* partials = (float*)(nseg + B_DIM);

    boundaries_kernel<<<B_DIM, 256, 0, stream>>>(bnd, seg, pos, nseg);
    pool_tiles_kernel<<<B_DIM * TPB, 256, 0, stream>>>(x, seg, partials);
    combine_kernel<<<B_DIM * MAXC, 256, 0, stream>>>(partials, seg, pos, nseg,
                                                     out_means, out_cnts);
}

// Round 7
// 31.817 us; speedup vs baseline: 1.1966x; 1.1966x over previous
//
#include <hip/hip_runtime.h>

// Problem constants (from reference): B=8, L=4096, D=1024, MAX_CHUNKS=128
#define B_DIM 8
#define L_DIM 4096
#define D_DIM 1024
#define MAXC 128
#define RG 4            // row groups per block
#define CT 256          // column threads (D/4 float4 slices)

__device__ __forceinline__ void f4add(float4& a, const float4& v) {
    a.x += v.x; a.y += v.y; a.z += v.z; a.w += v.w;
}

// ---------------------------------------------------------------------------
// Single fused kernel: one block per (batch, chunk), 1024 threads.
// Phase 1 (threads 0..255): scan this batch's boundary row in-block (16 KB,
//   L2-resident across the 128 blocks sharing a batch) and extract only
//   start = pos[c], end = pos[c+1] (or L), and n = #boundaries.
// Phase 2: mean-pool rows [start, end): 4 row-groups x 256 column threads,
//   8 independent accumulator chains per group, LDS reduce across groups.
// Empty/invalid chunks write zeros (d_out is poisoned by the harness).
// One dispatch total -- no workspace, no inter-kernel barrier.
// ---------------------------------------------------------------------------
__global__ __launch_bounds__(1024)
void fused_chunk_kernel(const float* __restrict__ x,
                        const float* __restrict__ bnd,
                        float* __restrict__ out_means,  // [B][MAXC][D]
                        float* __restrict__ out_cnts)   // [B][MAXC]
{
    const int bc = blockIdx.x;          // 0 .. B*MAXC-1
    const int b  = bc >> 7;             // / MAXC
    const int c  = bc & (MAXC - 1);
    const int t  = threadIdx.x;         // 0..1023
    const int tc = t & (CT - 1);        // column thread 0..255
    const int rg = t >> 8;              // row group 0..3

    __shared__ int s[256];
    __shared__ int sb[2];               // sb[0]=start, sb[1]=end
    __shared__ float4 red[RG][CT];      // 16 KB

    // ---- Phase 1: boundary scan ----
    if (t == 0) { sb[0] = 0; sb[1] = L_DIM; }

    unsigned m = 0u;
    int cnt16 = 0;
    if (t < 256) {
        const float* p = bnd + (size_t)b * L_DIM + t * 16;
        const float4* p4 = reinterpret_cast<const float4*>(p);
#pragma unroll
        for (int q = 0; q < 4; ++q) {
            float4 v = p4[q];
            if (v.x > 0.5f) m |= 1u << (q * 4 + 0);
            if (v.y > 0.5f) m |= 1u << (q * 4 + 1);
            if (v.z > 0.5f) m |= 1u << (q * 4 + 2);
            if (v.w > 0.5f) m |= 1u << (q * 4 + 3);
        }
        cnt16 = __popc(m);
        s[t] = cnt16;
    }
    __syncthreads();
    for (int off = 1; off < 256; off <<= 1) {
        int v = (t >= off && t < 256) ? s[t - off] : 0;
        __syncthreads();
        if (t < 256) s[t] += v;
        __syncthreads();
    }
    const int n = s[255];
    if (t < 256 && m != 0u) {
        int idx = s[t] - cnt16;         // exclusive prefix
        const int base = t * 16;
#pragma unroll
        for (int j = 0; j < 16; ++j) {
            if (m & (1u << j)) {
                if (idx == c)     sb[0] = base + j;
                if (idx == c + 1) sb[1] = base + j;
                ++idx;
            }
        }
    }
    __syncthreads();

    // ---- Phase 2: pool rows [start, end) ----
    int cnt = 0;
    float4 a0 = make_float4(0.f, 0.f, 0.f, 0.f);
    float4 a1 = a0, a2 = a0, a3 = a0, a4 = a0, a5 = a0, a6 = a0, a7 = a0;

    if (c < n) {
        const int start = sb[0];
        const int end   = sb[1];
        cnt = end - start;

        // this group's rows: r = rg + RG*k, k in [0, nr)
        const int nr = (cnt - rg + RG - 1) / RG;
        const float* xp = x + ((size_t)b * L_DIM + start + rg) * D_DIM + tc * 4;
        const size_t stride = (size_t)RG * D_DIM;   // floats between group rows

        int k = 0;
        const int rem = nr & 7;
        if (rem & 4) {
            float4 v0 = *reinterpret_cast<const float4*>(xp + (size_t)(k + 0) * stride);
            float4 v1 = *reinterpret_cast<const float4*>(xp + (size_t)(k + 1) * stride);
            float4 v2 = *reinterpret_cast<const float4*>(xp + (size_t)(k + 2) * stride);
            float4 v3 = *reinterpret_cast<const float4*>(xp + (size_t)(k + 3) * stride);
            f4add(a0, v0); f4add(a1, v1); f4add(a2, v2); f4add(a3, v3);
            k += 4;
        }
        if (rem & 2) {
            float4 v0 = *reinterpret_cast<const float4*>(xp + (size_t)(k + 0) * stride);
            float4 v1 = *reinterpret_cast<const float4*>(xp + (size_t)(k + 1) * stride);
            f4add(a4, v0); f4add(a5, v1);
            k += 2;
        }
        if (rem & 1) {
            float4 v0 = *reinterpret_cast<const float4*>(xp + (size_t)k * stride);
            f4add(a6, v0);
            k += 1;
        }
        for (; k + 8 <= nr; k += 8) {
            const float* base = xp + (size_t)k * stride;
            float4 v0 = *reinterpret_cast<const float4*>(base + 0 * stride);
            float4 v1 = *reinterpret_cast<const float4*>(base + 1 * stride);
            float4 v2 = *reinterpret_cast<const float4*>(base + 2 * stride);
            float4 v3 = *reinterpret_cast<const float4*>(base + 3 * stride);
            float4 v4 = *reinterpret_cast<const float4*>(base + 4 * stride);
            float4 v5 = *reinterpret_cast<const float4*>(base + 5 * stride);
            float4 v6 = *reinterpret_cast<const float4*>(base + 6 * stride);
            float4 v7 = *reinterpret_cast<const float4*>(base + 7 * stride);
            f4add(a0, v0); f4add(a1, v1); f4add(a2, v2); f4add(a3, v3);
            f4add(a4, v4); f4add(a5, v5); f4add(a6, v6); f4add(a7, v7);
        }
        f4add(a0, a1); f4add(a2, a3); f4add(a4, a5); f4add(a6, a7);
        f4add(a0, a2); f4add(a4, a6);
        f4add(a0, a4);
    }

    red[rg][tc] = a0;
    __syncthreads();

    if (t < CT) {
        float4 s0 = red[0][t];
        f4add(s0, red[1][t]);
        f4add(s0, red[2][t]);
        f4add(s0, red[3][t]);
        const float inv = (cnt > 0) ? (1.0f / (float)cnt) : 0.0f;
        s0.x *= inv; s0.y *= inv; s0.z *= inv; s0.w *= inv;
        float4* op = reinterpret_cast<float4*>(out_means + (size_t)bc * D_DIM) + t;
        *op = s0;
        if (t == 0) out_cnts[bc] = (float)cnt;
    }
}

extern "C" void kernel_launch(void* const* d_in, const int* in_sizes, int n_in,
                              void* d_out, int out_size, void* d_ws, size_t ws_size,
                              hipStream_t stream)
{
    const float* x   = (const float*)d_in[0];   // [B, L, D] fp32
    const float* bnd = (const float*)d_in[1];   // [B, L]    fp32

    float* out = (float*)d_out;
    float* out_means = out;                                // B*MAXC*D floats
    float* out_cnts  = out + (size_t)B_DIM * MAXC * D_DIM; // B*MAXC floats

    fused_chunk_kernel<<<B_DIM * MAXC, 1024, 0, stream>>>(x, bnd,
                                                          out_means, out_cnts);
}

// Round 8
// 31.653 us; speedup vs baseline: 1.2028x; 1.0052x over previous
//
#include <hip/hip_runtime.h>

// Problem constants (from reference): B=8, L=4096, D=1024, MAX_CHUNKS=128
#define B_DIM 8
#define L_DIM 4096
#define D_DIM 1024
#define MAXC 128
#define RG 4            // row groups per block
#define CT 256          // column threads (D/4 float4 slices)

__device__ __forceinline__ void f4add(float4& a, const float4& v) {
    a.x += v.x; a.y += v.y; a.z += v.z; a.w += v.w;
}

// ---------------------------------------------------------------------------
// Single fused kernel: one block per (batch, chunk), 1024 threads.
// Phase 1: all 1024 threads load 4 bnd floats (one float4 each = full row),
//   per-wave shfl_up inclusive scan of boundary counts (no barriers), wave
//   totals combined via LDS (2 barriers total). Extract start=pos[c],
//   end=pos[c+1] (or L), n = #boundaries.
// Phase 2: mean-pool rows [start, end): 4 row-groups x 256 column threads,
//   8 in-flight loads feeding 4 accumulator chains, LDS reduce across groups.
// __launch_bounds__(1024, 8): request 8 waves/EU = 32 waves/CU = 2 blocks/CU
//   co-resident -> forces VGPR <= 64.
// Empty/invalid chunks write zeros (d_out is poisoned by the harness).
// ---------------------------------------------------------------------------
__global__ __launch_bounds__(1024, 8)
void fused_chunk_kernel(const float* __restrict__ x,
                        const float* __restrict__ bnd,
                        float* __restrict__ out_means,  // [B][MAXC][D]
                        float* __restrict__ out_cnts)   // [B][MAXC]
{
    const int bc   = blockIdx.x;        // 0 .. B*MAXC-1
    const int b    = bc >> 7;           // / MAXC
    const int c    = bc & (MAXC - 1);
    const int t    = threadIdx.x;       // 0..1023
    const int tc   = t & (CT - 1);      // column thread 0..255
    const int rg   = t >> 8;            // row group 0..3
    const int lane = t & 63;
    const int w    = t >> 6;            // wave 0..15

    __shared__ int wtot[16];
    __shared__ int sb[2];               // sb[0]=start, sb[1]=end
    __shared__ float4 red[RG][CT];      // 16 KB

    if (t == 0) { sb[0] = 0; sb[1] = L_DIM; }

    // ---- Phase 1: boundary scan (wave-intrinsic) ----
    // thread t covers bnd[b][4t .. 4t+3]
    const float4 bv = reinterpret_cast<const float4*>(bnd + (size_t)b * L_DIM)[t];
    unsigned m = 0u;
    if (bv.x > 0.5f) m |= 1u;
    if (bv.y > 0.5f) m |= 2u;
    if (bv.z > 0.5f) m |= 4u;
    if (bv.w > 0.5f) m |= 8u;
    const int cnt4 = __popc(m);

    int incl = cnt4;
#pragma unroll
    for (int off = 1; off < 64; off <<= 1) {
        int u = __shfl_up(incl, off, 64);
        if (lane >= off) incl += u;
    }
    if (lane == 63) wtot[w] = incl;
    __syncthreads();

    int waveoff = 0, n = 0;
#pragma unroll
    for (int i = 0; i < 16; ++i) {
        const int ww = wtot[i];
        n += ww;
        if (i < w) waveoff += ww;
    }

    if (m != 0u) {
        int idx = waveoff + incl - cnt4;    // exclusive prefix
        const int base = t * 4;
#pragma unroll
        for (int j = 0; j < 4; ++j) {
            if (m & (1u << j)) {
                if (idx == c)     sb[0] = base + j;
                if (idx == c + 1) sb[1] = base + j;
                ++idx;
            }
        }
    }
    __syncthreads();

    // ---- Phase 2: pool rows [start, end) ----
    int cnt = 0;
    float4 a0 = make_float4(0.f, 0.f, 0.f, 0.f);
    float4 a1 = a0, a2 = a0, a3 = a0;

    if (c < n) {
        const int start = sb[0];
        const int end   = sb[1];
        cnt = end - start;

        // this group's rows: r = rg + RG*k, k in [0, nr)
        const int nr = (cnt - rg + RG - 1) / RG;
        const float* xp = x + ((size_t)b * L_DIM + start + rg) * D_DIM + tc * 4;
        const size_t stride = (size_t)RG * D_DIM;   // floats between group rows

        int k = 0;
        // main loop: 8 rows per iteration, 8 loads in flight, 4 acc chains
        for (; k + 8 <= nr; k += 8) {
            const float* base = xp + (size_t)k * stride;
            float4 v0 = *reinterpret_cast<const float4*>(base + 0 * stride);
            float4 v1 = *reinterpret_cast<const float4*>(base + 1 * stride);
            float4 v2 = *reinterpret_cast<const float4*>(base + 2 * stride);
            float4 v3 = *reinterpret_cast<const float4*>(base + 3 * stride);
            float4 v4 = *reinterpret_cast<const float4*>(base + 4 * stride);
            float4 v5 = *reinterpret_cast<const float4*>(base + 5 * stride);
            float4 v6 = *reinterpret_cast<const float4*>(base + 6 * stride);
            float4 v7 = *reinterpret_cast<const float4*>(base + 7 * stride);
            f4add(a0, v0); f4add(a1, v1); f4add(a2, v2); f4add(a3, v3);
            f4add(a0, v4); f4add(a1, v5); f4add(a2, v6); f4add(a3, v7);
        }
        // remainder (<= 7 rows), compile-time-indexed independent chains
        if (k + 4 <= nr) {
            const float* base = xp + (size_t)k * stride;
            float4 v0 = *reinterpret_cast<const float4*>(base + 0 * stride);
            float4 v1 = *reinterpret_cast<const float4*>(base + 1 * stride);
            float4 v2 = *reinterpret_cast<const float4*>(base + 2 * stride);
            float4 v3 = *reinterpret_cast<const float4*>(base + 3 * stride);
            f4add(a0, v0); f4add(a1, v1); f4add(a2, v2); f4add(a3, v3);
            k += 4;
        }
        if (k + 2 <= nr) {
            const float* base = xp + (size_t)k * stride;
            float4 v0 = *reinterpret_cast<const float4*>(base + 0 * stride);
            float4 v1 = *reinterpret_cast<const float4*>(base + 1 * stride);
            f4add(a0, v0); f4add(a1, v1);
            k += 2;
        }
        if (k < nr) {
            f4add(a2, *reinterpret_cast<const float4*>(xp + (size_t)k * stride));
        }
        f4add(a0, a1); f4add(a2, a3);
        f4add(a0, a2);
    }

    red[rg][tc] = a0;
    __syncthreads();

    if (t < CT) {
        float4 s0 = red[0][t];
        f4add(s0, red[1][t]);
        f4add(s0, red[2][t]);
        f4add(s0, red[3][t]);
        const float inv = (cnt > 0) ? (1.0f / (float)cnt) : 0.0f;
        s0.x *= inv; s0.y *= inv; s0.z *= inv; s0.w *= inv;
        float4* op = reinterpret_cast<float4*>(out_means + (size_t)bc * D_DIM) + t;
        *op = s0;
        if (t == 0) out_cnts[bc] = (float)cnt;
    }
}

extern "C" void kernel_launch(void* const* d_in, const int* in_sizes, int n_in,
                              void* d_out, int out_size, void* d_ws, size_t ws_size,
                              hipStream_t stream)
{
    const float* x   = (const float*)d_in[0];   // [B, L, D] fp32
    const float* bnd = (const float*)d_in[1];   // [B, L]    fp32

    float* out = (float*)d_out;
    float* out_means = out;                                // B*MAXC*D floats
    float* out_cnts  = out + (size_t)B_DIM * MAXC * D_DIM; // B*MAXC floats

    fused_chunk_kernel<<<B_DIM * MAXC, 1024, 0, stream>>>(x, bnd,
                                                          out_means, out_cnts);
}

// Round 9
// 28.996 us; speedup vs baseline: 1.3130x; 1.0916x over previous
//
#include <hip/hip_runtime.h>

// Problem constants (from reference): B=8, L=4096, D=1024, MAX_CHUNKS=128
#define B_DIM 8
#define L_DIM 4096
#define D_DIM 1024
#define MAXC 128
#define RG 4            // row groups per block (= waves per block)
#define SC 64           // float4 columns per block (D-quarter: 64*4 = 256 floats)

__device__ __forceinline__ void f4add(float4& a, const float4& v) {
    a.x += v.x; a.y += v.y; a.z += v.z; a.w += v.w;
}

// ---------------------------------------------------------------------------
// One block per (batch, chunk, D-quarter): grid = B*MAXC*4, 256 threads.
// Phase 1: scan this batch's boundary row (256 threads x 16 floats each,
//   per-wave shfl_up scan, 4 wave totals via LDS, 2 barriers) -> start/end/n.
// Phase 2: wave w (=row group) pools rows start+w, start+w+4, ... over its
//   64 float4 columns (1 KB contiguous per wave-load -> perfectly coalesced),
//   8 rows in flight per iteration, 4 accumulator chains; 4 KB LDS reduce.
// Rationale: quarter-size blocks cut the longest-chunk straggler 4x and give
//   the scheduler 4x finer grains; all data reads stay coalesced.
// Empty/invalid chunks write zeros (d_out is poisoned by the harness).
// ---------------------------------------------------------------------------
__global__ __launch_bounds__(256, 8)
void fused_chunk_kernel(const float* __restrict__ x,
                        const float* __restrict__ bnd,
                        float* __restrict__ out_means,  // [B][MAXC][D]
                        float* __restrict__ out_cnts)   // [B][MAXC]
{
    const int gid  = blockIdx.x;            // ((b*MAXC + c) << 2) | dq
    const int dq   = gid & 3;               // D-quarter 0..3
    const int bcC  = gid >> 2;              // b*MAXC + c
    const int b    = bcC >> 7;
    const int c    = bcC & (MAXC - 1);
    const int t    = threadIdx.x;           // 0..255
    const int lane = t & 63;
    const int wv   = t >> 6;                // wave = row group 0..3

    __shared__ int wtot[RG];
    __shared__ int sb[2];                   // sb[0]=start, sb[1]=end
    __shared__ float4 red[RG][SC];          // 4 KB

    if (t == 0) { sb[0] = 0; sb[1] = L_DIM; }

    // ---- Phase 1: boundary scan ----
    // thread t covers bnd[b][16t .. 16t+15]
    unsigned m = 0u;
    {
        const float4* p4 = reinterpret_cast<const float4*>(bnd + (size_t)b * L_DIM) + t * 4;
        float4 v0 = p4[0], v1 = p4[1], v2 = p4[2], v3 = p4[3];
        if (v0.x > 0.5f) m |= 1u << 0;
        if (v0.y > 0.5f) m |= 1u << 1;
        if (v0.z > 0.5f) m |= 1u << 2;
        if (v0.w > 0.5f) m |= 1u << 3;
        if (v1.x > 0.5f) m |= 1u << 4;
        if (v1.y > 0.5f) m |= 1u << 5;
        if (v1.z > 0.5f) m |= 1u << 6;
        if (v1.w > 0.5f) m |= 1u << 7;
        if (v2.x > 0.5f) m |= 1u << 8;
        if (v2.y > 0.5f) m |= 1u << 9;
        if (v2.z > 0.5f) m |= 1u << 10;
        if (v2.w > 0.5f) m |= 1u << 11;
        if (v3.x > 0.5f) m |= 1u << 12;
        if (v3.y > 0.5f) m |= 1u << 13;
        if (v3.z > 0.5f) m |= 1u << 14;
        if (v3.w > 0.5f) m |= 1u << 15;
    }
    const int cnt16 = __popc(m);

    int incl = cnt16;
#pragma unroll
    for (int off = 1; off < 64; off <<= 1) {
        int u = __shfl_up(incl, off, 64);
        if (lane >= off) incl += u;
    }
    if (lane == 63) wtot[wv] = incl;
    __syncthreads();

    int waveoff = 0, n = 0;
#pragma unroll
    for (int i = 0; i < RG; ++i) {
        const int ww = wtot[i];
        n += ww;
        if (i < wv) waveoff += ww;
    }

    if (m != 0u) {
        int idx = waveoff + incl - cnt16;   // exclusive prefix
        const int base = t * 16;
#pragma unroll
        for (int j = 0; j < 16; ++j) {
            if (m & (1u << j)) {
                if (idx == c)     sb[0] = base + j;
                if (idx == c + 1) sb[1] = base + j;
                ++idx;
            }
        }
    }
    __syncthreads();

    // ---- Phase 2: pool rows [start, end) over this block's 64 f4 columns ----
    int cnt = 0;
    float4 a0 = make_float4(0.f, 0.f, 0.f, 0.f);
    float4 a1 = a0, a2 = a0, a3 = a0;

    if (c < n) {
        const int start = sb[0];
        const int end   = sb[1];
        cnt = end - start;

        // this wave's rows: r = wv + RG*k, k in [0, nr)
        const int nr = (cnt - wv + RG - 1) / RG;
        const float* xp = x + ((size_t)b * L_DIM + start + wv) * D_DIM
                            + (size_t)(dq * SC + lane) * 4;
        const size_t stride = (size_t)RG * D_DIM;   // floats between wave rows

        int k = 0;
        for (; k + 8 <= nr; k += 8) {
            const float* base = xp + (size_t)k * stride;
            float4 v0 = *reinterpret_cast<const float4*>(base + 0 * stride);
            float4 v1 = *reinterpret_cast<const float4*>(base + 1 * stride);
            float4 v2 = *reinterpret_cast<const float4*>(base + 2 * stride);
            float4 v3 = *reinterpret_cast<const float4*>(base + 3 * stride);
            float4 v4 = *reinterpret_cast<const float4*>(base + 4 * stride);
            float4 v5 = *reinterpret_cast<const float4*>(base + 5 * stride);
            float4 v6 = *reinterpret_cast<const float4*>(base + 6 * stride);
            float4 v7 = *reinterpret_cast<const float4*>(base + 7 * stride);
            f4add(a0, v0); f4add(a1, v1); f4add(a2, v2); f4add(a3, v3);
            f4add(a0, v4); f4add(a1, v5); f4add(a2, v6); f4add(a3, v7);
        }
        if (k + 4 <= nr) {
            const float* base = xp + (size_t)k * stride;
            float4 v0 = *reinterpret_cast<const float4*>(base + 0 * stride);
            float4 v1 = *reinterpret_cast<const float4*>(base + 1 * stride);
            float4 v2 = *reinterpret_cast<const float4*>(base + 2 * stride);
            float4 v3 = *reinterpret_cast<const float4*>(base + 3 * stride);
            f4add(a0, v0); f4add(a1, v1); f4add(a2, v2); f4add(a3, v3);
            k += 4;
        }
        if (k + 2 <= nr) {
            const float* base = xp + (size_t)k * stride;
            float4 v0 = *reinterpret_cast<const float4*>(base + 0 * stride);
            float4 v1 = *reinterpret_cast<const float4*>(base + 1 * stride);
            f4add(a0, v0); f4add(a1, v1);
            k += 2;
        }
        if (k < nr) {
            f4add(a2, *reinterpret_cast<const float4*>(xp + (size_t)k * stride));
        }
        f4add(a0, a1); f4add(a2, a3);
        f4add(a0, a2);
    }

    red[wv][lane] = a0;
    __syncthreads();

    if (t < SC) {
        float4 s0 = red[0][t];
        f4add(s0, red[1][t]);
        f4add(s0, red[2][t]);
        f4add(s0, red[3][t]);
        const float inv = (cnt > 0) ? (1.0f / (float)cnt) : 0.0f;
        s0.x *= inv; s0.y *= inv; s0.z *= inv; s0.w *= inv;
        float4* op = reinterpret_cast<float4*>(out_means + (size_t)bcC * D_DIM)
                     + dq * SC + t;
        *op = s0;
        if (t == 0 && dq == 0) out_cnts[bcC] = (float)cnt;
    }
}

extern "C" void kernel_launch(void* const* d_in, const int* in_sizes, int n_in,
                              void* d_out, int out_size, void* d_ws, size_t ws_size,
                              hipStream_t stream)
{
    const float* x   = (const float*)d_in[0];   // [B, L, D] fp32
    const float* bnd = (const float*)d_in[1];   // [B, L]    fp32

    float* out = (float*)d_out;
    float* out_means = out;                                // B*MAXC*D floats
    float* out_cnts  = out + (size_t)B_DIM * MAXC * D_DIM; // B*MAXC floats

    fused_chunk_kernel<<<B_DIM * MAXC * 4, 256, 0, stream>>>(x, bnd,
                                                             out_means, out_cnts);
}

// Round 10
// 28.508 us; speedup vs baseline: 1.3355x; 1.0171x over previous
//
#include <hip/hip_runtime.h>

// Problem constants (from reference): B=8, L=4096, D=1024, MAX_CHUNKS=128
#define B_DIM 8
#define L_DIM 4096
#define D_DIM 1024
#define MAXC 128
#define RG 4            // waves per block (row groups)
#define SC 64           // float4 columns per block (D-quarter)

__device__ __forceinline__ void f4add(float4& a, const float4& v) {
    a.x += v.x; a.y += v.y; a.z += v.z; a.w += v.w;
}

// ---------------------------------------------------------------------------
// One block per (batch, chunk, D-quarter): grid = B*MAXC*4, 256 threads.
// Block-id swizzle maps batch b -> XCD b (round-robin dispatch): all 512
//   blocks of a batch share one XCD L2 (bnd row stays hot; chunk dq-blocks
//   co-located).
// Phase 1: boundary scan (shfl_up per wave + LDS wave totals) -> start/end/n.
// Phase 2: wave wv pools a CONTIGUOUS quarter of the chunk's rows over its
//   64 float4 columns -- loads advance sequentially at 4 KB stride, 8 rows
//   (32 KB window) in flight; 4 accumulator chains; 4 KB LDS reduce.
// Empty/invalid chunks write zeros (d_out is poisoned by the harness).
// ---------------------------------------------------------------------------
__global__ __launch_bounds__(256, 8)
void fused_chunk_kernel(const float* __restrict__ x,
                        const float* __restrict__ bnd,
                        float* __restrict__ out_means,  // [B][MAXC][D]
                        float* __restrict__ out_cnts)   // [B][MAXC]
{
    // swizzle: g = blockIdx.x; batch = g&7 (-> XCD g%8), unit-in-batch = g>>3
    const int g    = blockIdx.x;
    const int b    = g & 7;
    const int u    = g >> 3;            // 0..511 = (c<<2)|dq
    const int dq   = u & 3;
    const int c    = u >> 2;
    const int bcC  = b * MAXC + c;
    const int t    = threadIdx.x;       // 0..255
    const int lane = t & 63;
    const int wv   = t >> 6;            // wave 0..3

    __shared__ int wtot[RG];
    __shared__ int sb[2];               // sb[0]=start, sb[1]=end
    __shared__ float4 red[RG][SC];      // 4 KB

    if (t == 0) { sb[0] = 0; sb[1] = L_DIM; }

    // ---- Phase 1: boundary scan (thread t covers bnd[b][16t..16t+15]) ----
    unsigned m = 0u;
    {
        const float4* p4 = reinterpret_cast<const float4*>(bnd + (size_t)b * L_DIM) + t * 4;
        float4 v0 = p4[0], v1 = p4[1], v2 = p4[2], v3 = p4[3];
        if (v0.x > 0.5f) m |= 1u << 0;
        if (v0.y > 0.5f) m |= 1u << 1;
        if (v0.z > 0.5f) m |= 1u << 2;
        if (v0.w > 0.5f) m |= 1u << 3;
        if (v1.x > 0.5f) m |= 1u << 4;
        if (v1.y > 0.5f) m |= 1u << 5;
        if (v1.z > 0.5f) m |= 1u << 6;
        if (v1.w > 0.5f) m |= 1u << 7;
        if (v2.x > 0.5f) m |= 1u << 8;
        if (v2.y > 0.5f) m |= 1u << 9;
        if (v2.z > 0.5f) m |= 1u << 10;
        if (v2.w > 0.5f) m |= 1u << 11;
        if (v3.x > 0.5f) m |= 1u << 12;
        if (v3.y > 0.5f) m |= 1u << 13;
        if (v3.z > 0.5f) m |= 1u << 14;
        if (v3.w > 0.5f) m |= 1u << 15;
    }
    const int cnt16 = __popc(m);

    int incl = cnt16;
#pragma unroll
    for (int off = 1; off < 64; off <<= 1) {
        int uu = __shfl_up(incl, off, 64);
        if (lane >= off) incl += uu;
    }
    if (lane == 63) wtot[wv] = incl;
    __syncthreads();

    int waveoff = 0, n = 0;
#pragma unroll
    for (int i = 0; i < RG; ++i) {
        const int ww = wtot[i];
        n += ww;
        if (i < wv) waveoff += ww;
    }

    if (m != 0u) {
        int idx = waveoff + incl - cnt16;   // exclusive prefix
        const int base = t * 16;
#pragma unroll
        for (int j = 0; j < 16; ++j) {
            if (m & (1u << j)) {
                if (idx == c)     sb[0] = base + j;
                if (idx == c + 1) sb[1] = base + j;
                ++idx;
            }
        }
    }
    __syncthreads();

    // ---- Phase 2: pool a contiguous quarter of rows over 64 f4 columns ----
    int cnt = 0;
    float4 a0 = make_float4(0.f, 0.f, 0.f, 0.f);
    float4 a1 = a0, a2 = a0, a3 = a0;

    if (c < n) {
        const int start = sb[0];
        const int end   = sb[1];
        cnt = end - start;

        // contiguous quarter for this wave
        const int q = cnt >> 2;
        const int r = cnt & 3;
        const int len = q + (wv < r ? 1 : 0);
        const int off = wv * q + (wv < r ? wv : r);

        const float* xp = x + ((size_t)b * L_DIM + start + off) * D_DIM
                            + (size_t)(dq * SC + lane) * 4;
        const size_t stride = (size_t)D_DIM;    // 4 KB: consecutive rows

        int k = 0;
        for (; k + 8 <= len; k += 8) {
            const float* base = xp + (size_t)k * stride;
            float4 v0 = *reinterpret_cast<const float4*>(base + 0 * stride);
            float4 v1 = *reinterpret_cast<const float4*>(base + 1 * stride);
            float4 v2 = *reinterpret_cast<const float4*>(base + 2 * stride);
            float4 v3 = *reinterpret_cast<const float4*>(base + 3 * stride);
            float4 v4 = *reinterpret_cast<const float4*>(base + 4 * stride);
            float4 v5 = *reinterpret_cast<const float4*>(base + 5 * stride);
            float4 v6 = *reinterpret_cast<const float4*>(base + 6 * stride);
            float4 v7 = *reinterpret_cast<const float4*>(base + 7 * stride);
            f4add(a0, v0); f4add(a1, v1); f4add(a2, v2); f4add(a3, v3);
            f4add(a0, v4); f4add(a1, v5); f4add(a2, v6); f4add(a3, v7);
        }
        if (k + 4 <= len) {
            const float* base = xp + (size_t)k * stride;
            float4 v0 = *reinterpret_cast<const float4*>(base + 0 * stride);
            float4 v1 = *reinterpret_cast<const float4*>(base + 1 * stride);
            float4 v2 = *reinterpret_cast<const float4*>(base + 2 * stride);
            float4 v3 = *reinterpret_cast<const float4*>(base + 3 * stride);
            f4add(a0, v0); f4add(a1, v1); f4add(a2, v2); f4add(a3, v3);
            k += 4;
        }
        if (k + 2 <= len) {
            const float* base = xp + (size_t)k * stride;
            float4 v0 = *reinterpret_cast<const float4*>(base + 0 * stride);
            float4 v1 = *reinterpret_cast<const float4*>(base + 1 * stride);
            f4add(a0, v0); f4add(a1, v1);
            k += 2;
        }
        if (k < len) {
            f4add(a2, *reinterpret_cast<const float4*>(xp + (size_t)k * stride));
        }
        f4add(a0, a1); f4add(a2, a3);
        f4add(a0, a2);
    }

    red[wv][lane] = a0;
    __syncthreads();

    if (t < SC) {
        float4 s0 = red[0][t];
        f4add(s0, red[1][t]);
        f4add(s0, red[2][t]);
        f4add(s0, red[3][t]);
        const float inv = (cnt > 0) ? (1.0f / (float)cnt) : 0.0f;
        s0.x *= inv; s0.y *= inv; s0.z *= inv; s0.w *= inv;
        float4* op = reinterpret_cast<float4*>(out_means + (size_t)bcC * D_DIM)
                     + dq * SC + t;
        *op = s0;
        if (t == 0 && dq == 0) out_cnts[bcC] = (float)cnt;
    }
}

extern "C" void kernel_launch(void* const* d_in, const int* in_sizes, int n_in,
                              void* d_out, int out_size, void* d_ws, size_t ws_size,
                              hipStream_t stream)
{
    const float* x   = (const float*)d_in[0];   // [B, L, D] fp32
    const float* bnd = (const float*)d_in[1];   // [B, L]    fp32

    float* out = (float*)d_out;
    float* out_means = out;                                // B*MAXC*D floats
    float* out_cnts  = out + (size_t)B_DIM * MAXC * D_DIM; // B*MAXC floats

    fused_chunk_kernel<<<B_DIM * MAXC * 4, 256, 0, stream>>>(x, bnd,
                                                             out_means, out_cnts);
}